// Round 3
// baseline (3733.249 us; speedup 1.0000x reference)
//
#include <hip/hip_runtime.h>

#define DEVINL __device__ __forceinline__

DEVINL void fma4(float4& a, const float4 w, const float x) {
    a.x += w.x * x; a.y += w.y * x; a.z += w.z * x; a.w += w.w * x;
}

// ===========================================================================
// CSR build: counting sort of edges by dst.
// ===========================================================================
__global__ __launch_bounds__(256) void hist_kernel(const int* __restrict__ d,
                                                   int* __restrict__ counts, int n) {
    for (int i = blockIdx.x * 256 + threadIdx.x; i < n; i += gridDim.x * 256)
        atomicAdd(&counts[d[i]], 1);
}

__global__ __launch_bounds__(1024) void scan_block(const int* __restrict__ in,
                                                   int* __restrict__ out,
                                                   int* __restrict__ bsums, int n) {
    __shared__ int buf[2][1024];
    const int t = threadIdx.x;
    const int i = blockIdx.x * 1024 + t;
    const int v = (i < n) ? in[i] : 0;
    int cur = 0;
    buf[0][t] = v;
    __syncthreads();
    #pragma unroll
    for (int s = 1; s < 1024; s <<= 1) {
        int x = buf[cur][t];
        if (t >= s) x += buf[cur][t - s];
        buf[cur ^ 1][t] = x;
        cur ^= 1;
        __syncthreads();
    }
    if (i < n) out[i] = buf[cur][t] - v;          // exclusive
    if (t == 1023) bsums[blockIdx.x] = buf[cur][t]; // block total
}

__global__ void scan_small(int* __restrict__ bs, int nb) {
    if (blockIdx.x == 0 && threadIdx.x == 0) {
        int acc = 0;
        for (int i = 0; i < nb; i++) { int v = bs[i]; bs[i] = acc; acc += v; }
    }
}

__global__ __launch_bounds__(1024) void add_offsets(int* __restrict__ out,
                                                    const int* __restrict__ bs, int n) {
    int i = blockIdx.x * 1024 + threadIdx.x;
    if (i < n) out[i] += bs[blockIdx.x];
}

__global__ __launch_bounds__(256) void scatter_kernel(const int* __restrict__ d,
                                                      int* __restrict__ cursor,
                                                      int* __restrict__ eidS,
                                                      int* __restrict__ dS, int n) {
    for (int i = blockIdx.x * 256 + threadIdx.x; i < n; i += gridDim.x * 256) {
        int dd = d[i];
        int pos = atomicAdd(&cursor[dd], 1);
        eidS[pos] = i;
        dS[pos] = dd;
    }
}

// ===========================================================================
// Edge kernel (dst-sorted): thread-per-edge GEMV m = relu(cat(h[src],e)@W+b),
// then per-half (128 sorted edges) LDS segmented reduction by dst and ~1
// atomic per (segment, feature) instead of 50 atomics per edge.
// MS = LDS message row stride in dwords (odd => conflict-free).
// Grid sized exactly: nEdges % 256 == 0.
// ===========================================================================
template<int FIN, int FINP, int FOUT, int FOUTP, int MS>
__global__ __launch_bounds__(256) void edge_kernel(
    const float* __restrict__ h,
    const float* __restrict__ efeats,
    const int* __restrict__ src,
    const int* __restrict__ eidS,
    const int* __restrict__ dS,
    const float* __restrict__ W,
    const float* __restrict__ b,
    float* __restrict__ agg)
{
    constexpr int K   = FINP + 64;              // padded input length
    constexpr int F4  = FOUTP / 4;
    constexpr int WSZ = K * F4;                 // W tile, in float4
    constexpr int MSZ = (128 * MS + 64 + 3) / 4; // msg buf (+64 lane-read pad)
    constexpr int SM4 = (WSZ > MSZ) ? WSZ : MSZ;

    __shared__ float4 smem[SM4];   // union: W tile (compute) / msg (reduce)
    __shared__ float  bl[FOUTP];
    __shared__ int    dhalf[128];

    float4* Wl  = smem;
    float*  msg = reinterpret_cast<float*>(smem);

    const int tid = threadIdx.x;

    // Stage padded W: rows [0,FIN)=h-part, [FIN,FINP)=0, [FINP,FINP+64)=e-part.
    for (int idx = tid; idx < K * FOUTP; idx += 256) {
        int k = idx / FOUTP;
        int j = idx - k * FOUTP;
        float v = 0.f;
        if (j < FOUT) {
            if (k < FIN)        v = W[k * FOUT + j];
            else if (k >= FINP) v = W[(FIN + (k - FINP)) * FOUT + j];
        }
        reinterpret_cast<float*>(Wl)[idx] = v;
    }
    if (tid < FOUTP) bl[tid] = (tid < FOUT) ? b[tid] : 0.f;
    __syncthreads();

    const int p    = blockIdx.x * 256 + tid;   // sorted position
    const int eid  = eidS[p];
    const int myD  = dS[p];
    const int sIdx = src[eid];
    const float4* erow = reinterpret_cast<const float4*>(efeats + (long long)eid * 64);
    const float4* hrow = reinterpret_cast<const float4*>(h + (long long)sIdx * FINP);

    float4 acc[F4];
    #pragma unroll
    for (int j4 = 0; j4 < F4; j4++) acc[j4] = reinterpret_cast<float4*>(bl)[j4];

    // h[src] part
    #pragma unroll
    for (int k4 = 0; k4 < FINP / 4; k4++) {
        float4 xv = hrow[k4];
        #pragma unroll
        for (int c = 0; c < 4; c++) {
            float xc = (c == 0) ? xv.x : (c == 1) ? xv.y : (c == 2) ? xv.z : xv.w;
            const float4* wrow = &Wl[(k4 * 4 + c) * F4];
            #pragma unroll
            for (int j4 = 0; j4 < F4; j4++) fma4(acc[j4], wrow[j4], xc);
        }
    }
    // efeat part
    #pragma unroll
    for (int k4 = 0; k4 < 16; k4++) {
        float4 xv = erow[k4];
        #pragma unroll
        for (int c = 0; c < 4; c++) {
            float xc = (c == 0) ? xv.x : (c == 1) ? xv.y : (c == 2) ? xv.z : xv.w;
            const float4* wrow = &Wl[(FINP + k4 * 4 + c) * F4];
            #pragma unroll
            for (int j4 = 0; j4 < F4; j4++) fma4(acc[j4], wrow[j4], xc);
        }
    }

    __syncthreads();   // all W reads done; smem reused for messages

    const int lane = tid & 63;
    const int wv   = tid >> 6;

    #pragma unroll
    for (int half = 0; half < 2; ++half) {
        // owners of this half store relu(msg) + dst
        if ((tid >> 7) == half) {
            const int le = tid & 127;
            dhalf[le] = myD;
            #pragma unroll
            for (int j4 = 0; j4 < F4; j4++) {
                float4 a = acc[j4];
                if (4 * j4 + 0 < FOUT) msg[le * MS + 4 * j4 + 0] = fmaxf(a.x, 0.f);
                if (4 * j4 + 1 < FOUT) msg[le * MS + 4 * j4 + 1] = fmaxf(a.y, 0.f);
                if (4 * j4 + 2 < FOUT) msg[le * MS + 4 * j4 + 2] = fmaxf(a.z, 0.f);
                if (4 * j4 + 3 < FOUT) msg[le * MS + 4 * j4 + 3] = fmaxf(a.w, 0.f);
            }
        }
        __syncthreads();

        // segmented reduce: wave wv walks rows [wv*32, wv*32+32); lane=feature.
        // Segment flags are wave-uniform (scalar LDS broadcasts) => no divergence.
        for (int r = wv * 32; r < wv * 32 + 32; ++r) {
            int dr = dhalf[r];
            if (r > 0 && dhalf[r - 1] == dr) continue;   // not a segment start
            float s = 0.f;
            int rr = r;
            while (true) {
                s += msg[rr * MS + lane];
                ++rr;
                if (rr >= 128 || dhalf[rr] != dr) break;
            }
            if (lane < FOUT) atomicAdd(agg + (long long)dr * FOUT + lane, s);
        }
        __syncthreads();
    }
}

// ===========================================================================
// Node kernel: out = relu(cat(h, agg) @ W + b), one thread per node.
// ===========================================================================
template<int FH, int FHP, int FAGG, int FOUT, int FOUTP>
__global__ __launch_bounds__(256) void node_kernel(
    const float* __restrict__ h,
    const float* __restrict__ agg,
    const float* __restrict__ W,
    const float* __restrict__ b,
    float* __restrict__ out,
    int nNodes)
{
    constexpr int K  = FH + FAGG;
    constexpr int F4 = FOUTP / 4;

    __shared__ float4 Wl[K * F4];
    __shared__ float4 bl[F4];

    const int tid = threadIdx.x;
    for (int idx = tid; idx < K * FOUTP; idx += 256) {
        int k = idx / FOUTP;
        int j = idx - k * FOUTP;
        reinterpret_cast<float*>(Wl)[idx] = (j < FOUT) ? W[k * FOUT + j] : 0.f;
    }
    for (int idx = tid; idx < FOUTP; idx += 256)
        reinterpret_cast<float*>(bl)[idx] = (idx < FOUT) ? b[idx] : 0.f;
    __syncthreads();

    const int n = blockIdx.x * 256 + tid;
    if (n >= nNodes) return;

    float4 acc[F4];
    #pragma unroll
    for (int j4 = 0; j4 < F4; j4++) acc[j4] = bl[j4];

    const float* hrow = h + (long long)n * FHP;
    for (int k = 0; k < FH; k++) {
        float xk = hrow[k];
        const float4* wrow = &Wl[k * F4];
        #pragma unroll
        for (int j4 = 0; j4 < F4; j4++) fma4(acc[j4], wrow[j4], xk);
    }
    const float* arow = agg + (long long)n * FAGG;
    for (int k = 0; k < FAGG; k++) {
        float xk = arow[k];
        const float4* wrow = &Wl[(FH + k) * F4];
        #pragma unroll
        for (int j4 = 0; j4 < F4; j4++) fma4(acc[j4], wrow[j4], xk);
    }

    float4* orow = reinterpret_cast<float4*>(out + (long long)n * FOUTP);
    #pragma unroll
    for (int j4 = 0; j4 < F4; j4++) {
        float4 a = acc[j4];
        a.x = fmaxf(a.x, 0.f); a.y = fmaxf(a.y, 0.f);
        a.z = fmaxf(a.z, 0.f); a.w = fmaxf(a.w, 0.f);
        orow[j4] = a;
    }
}

extern "C" void kernel_launch(void* const* d_in, const int* in_sizes, int n_in,
                              void* d_out, int out_size, void* d_ws, size_t ws_size,
                              hipStream_t stream)
{
    const float* nfeats = (const float*)d_in[0];
    const float* efeats = (const float*)d_in[1];
    const int*   src    = (const int*)d_in[2];
    const int*   dst    = (const int*)d_in[3];
    const float* Wm1 = (const float*)d_in[4],  *bm1 = (const float*)d_in[5];
    const float* Wa1 = (const float*)d_in[6],  *ba1 = (const float*)d_in[7];
    const float* Wm2 = (const float*)d_in[8],  *bm2 = (const float*)d_in[9];
    const float* Wa2 = (const float*)d_in[10], *ba2 = (const float*)d_in[11];
    const float* Wm3 = (const float*)d_in[12], *bm3 = (const float*)d_in[13];
    const float* Wa3 = (const float*)d_in[14], *ba3 = (const float*)d_in[15];
    float* out = (float*)d_out;

    constexpr int N = 100000;
    constexpr int E = 3200000;               // divisible by 256
    constexpr int SCAN_BLOCKS = (N + 1023) / 1024;   // 98

    float* ws   = (float*)d_ws;
    float* h1   = ws;                         // N x 52
    float* h2   = h1 + (size_t)N * 52;        // N x 28
    float* agg  = h2 + (size_t)N * 28;        // N x 52
    int* counts = (int*)(agg + (size_t)N * 52);  // N
    int* cursor = counts + N;                    // N
    int* bsums  = cursor + N;                    // 128
    int* eidS   = bsums + 128;                   // E
    int* dS     = eidS + E;                      // E
    // total ~79.2 MB

    // ---- CSR build (counting sort by dst) ----
    hipMemsetAsync(counts, 0, (size_t)N * sizeof(int), stream);
    hist_kernel<<<2048, 256, 0, stream>>>(dst, counts, E);
    scan_block<<<SCAN_BLOCKS, 1024, 0, stream>>>(counts, cursor, bsums, N);
    scan_small<<<1, 64, 0, stream>>>(bsums, SCAN_BLOCKS);
    add_offsets<<<SCAN_BLOCKS, 1024, 0, stream>>>(cursor, bsums, N);
    scatter_kernel<<<2048, 256, 0, stream>>>(dst, cursor, eidS, dS, E);

    const int EB = E / 256;
    const int NB = (N + 255) / 256;

    // ---- layer 1 ----  edge: 64(+64) -> 50 (MS=51); node: 64+50 -> 50
    hipMemsetAsync(agg, 0, (size_t)N * 52 * sizeof(float), stream);
    edge_kernel<64, 64, 50, 52, 51><<<EB, 256, 0, stream>>>(nfeats, efeats, src, eidS, dS, Wm1, bm1, agg);
    node_kernel<64, 64, 50, 50, 52><<<NB, 256, 0, stream>>>(nfeats, agg, Wa1, ba1, h1, N);

    // ---- layer 2 ----  edge: 50(+64) -> 25 (MS=25); node: 50+25 -> 25
    hipMemsetAsync(agg, 0, (size_t)N * 52 * sizeof(float), stream);
    edge_kernel<50, 52, 25, 28, 25><<<EB, 256, 0, stream>>>(h1, efeats, src, eidS, dS, Wm2, bm2, agg);
    node_kernel<50, 52, 25, 25, 28><<<NB, 256, 0, stream>>>(h1, agg, Wa2, ba2, h2, N);

    // ---- layer 3 ----  edge: 25(+64) -> 32 (MS=33); node: 25+32 -> 32
    hipMemsetAsync(agg, 0, (size_t)N * 52 * sizeof(float), stream);
    edge_kernel<25, 28, 32, 32, 33><<<EB, 256, 0, stream>>>(h2, efeats, src, eidS, dS, Wm3, bm3, agg);
    node_kernel<25, 28, 32, 32, 32><<<NB, 256, 0, stream>>>(h2, agg, Wa3, ba3, out, N);
}

// Round 4
// 3529.950 us; speedup vs baseline: 1.0576x; 1.0576x over previous
//
#include <hip/hip_runtime.h>

#define DEVINL __device__ __forceinline__

DEVINL void fma4(float4& a, const float4 w, const float x) {
    a.x += w.x * x; a.y += w.y * x; a.z += w.z * x; a.w += w.w * x;
}

// ===========================================================================
// CSR build: counting sort of edges by dst.
// ===========================================================================
__global__ __launch_bounds__(256) void hist_kernel(const int* __restrict__ d,
                                                   int* __restrict__ counts, int n) {
    for (int i = blockIdx.x * 256 + threadIdx.x; i < n; i += gridDim.x * 256)
        atomicAdd(&counts[d[i]], 1);
}

__global__ __launch_bounds__(1024) void scan_block(const int* __restrict__ in,
                                                   int* __restrict__ out,
                                                   int* __restrict__ bsums, int n) {
    __shared__ int buf[2][1024];
    const int t = threadIdx.x;
    const int i = blockIdx.x * 1024 + t;
    const int v = (i < n) ? in[i] : 0;
    int cur = 0;
    buf[0][t] = v;
    __syncthreads();
    #pragma unroll
    for (int s = 1; s < 1024; s <<= 1) {
        int x = buf[cur][t];
        if (t >= s) x += buf[cur][t - s];
        buf[cur ^ 1][t] = x;
        cur ^= 1;
        __syncthreads();
    }
    if (i < n) out[i] = buf[cur][t] - v;            // exclusive
    if (t == 1023) bsums[blockIdx.x] = buf[cur][t]; // block total
}

__global__ void scan_small(int* __restrict__ bs, int nb) {
    if (blockIdx.x == 0 && threadIdx.x == 0) {
        int acc = 0;
        for (int i = 0; i < nb; i++) { int v = bs[i]; bs[i] = acc; acc += v; }
    }
}

__global__ __launch_bounds__(1024) void add_offsets(int* __restrict__ out,
                                                    const int* __restrict__ bs, int n) {
    int i = blockIdx.x * 1024 + threadIdx.x;
    if (i < n) out[i] += bs[blockIdx.x];
}

__global__ __launch_bounds__(256) void scatter_kernel(const int* __restrict__ d,
                                                      int* __restrict__ cursor,
                                                      int* __restrict__ eidS,
                                                      int* __restrict__ dS, int n) {
    for (int i = blockIdx.x * 256 + threadIdx.x; i < n; i += gridDim.x * 256) {
        int dd = d[i];
        int pos = atomicAdd(&cursor[dd], 1);
        eidS[pos] = i;
        dS[pos] = dd;
    }
}

// ===========================================================================
// Edge kernel (dst-sorted): thread-per-edge GEMV m = relu(cat(h[src],e)@W+b).
// Input rows are BURST-LOADED into registers (back-to-back dwordx4) so each
// cache line is fetched once; the previous interleaved load/FMA pattern had
// an ~800-cycle reuse window and re-fetched evicted lines up to 8x.
// Then per-half (128 sorted edges) LDS segmented reduction by dst, ~1 atomic
// per (segment, feature). MS = LDS msg row stride (odd => conflict-free).
// Grid sized exactly: nEdges % 256 == 0.
// ===========================================================================
template<int FIN, int FINP, int FOUT, int FOUTP, int MS>
__global__ __launch_bounds__(256) void edge_kernel(
    const float* __restrict__ h,
    const float* __restrict__ efeats,
    const int* __restrict__ src,
    const int* __restrict__ eidS,
    const int* __restrict__ dS,
    const float* __restrict__ W,
    const float* __restrict__ b,
    float* __restrict__ agg)
{
    constexpr int K   = FINP + 64;               // padded input length
    constexpr int F4  = FOUTP / 4;
    constexpr int H4  = FINP / 4;
    constexpr int WSZ = K * F4;                  // W tile, in float4
    constexpr int MSZ = (128 * MS + 64 + 3) / 4; // msg buf (+64 lane-read pad)
    constexpr int SM4 = (WSZ > MSZ) ? WSZ : MSZ;

    __shared__ float4 smem[SM4];   // union: W tile (compute) / msg (reduce)
    __shared__ float  bl[FOUTP];
    __shared__ int    dhalf[128];

    float4* Wl  = smem;
    float*  msg = reinterpret_cast<float*>(smem);

    const int tid = threadIdx.x;

    // Stage padded W: rows [0,FIN)=h-part, [FIN,FINP)=0, [FINP,FINP+64)=e-part.
    for (int idx = tid; idx < K * FOUTP; idx += 256) {
        int k = idx / FOUTP;
        int j = idx - k * FOUTP;
        float v = 0.f;
        if (j < FOUT) {
            if (k < FIN)        v = W[k * FOUT + j];
            else if (k >= FINP) v = W[(FIN + (k - FINP)) * FOUT + j];
        }
        reinterpret_cast<float*>(Wl)[idx] = v;
    }
    if (tid < FOUTP) bl[tid] = (tid < FOUT) ? b[tid] : 0.f;
    __syncthreads();

    const int p    = blockIdx.x * 256 + tid;   // sorted position
    const int eid  = eidS[p];
    const int myD  = dS[p];
    const int sIdx = src[eid];
    const float4* erow = reinterpret_cast<const float4*>(efeats + (long long)eid * 64);
    const float4* hrow = reinterpret_cast<const float4*>(h + (long long)sIdx * FINP);

    // ---- burst loads: every line of both rows fetched exactly once ----
    float4 hr[H4];
    #pragma unroll
    for (int k4 = 0; k4 < H4; k4++) hr[k4] = hrow[k4];
    float4 er[16];
    #pragma unroll
    for (int k4 = 0; k4 < 16; k4++) er[k4] = erow[k4];

    float4 acc[F4];
    #pragma unroll
    for (int j4 = 0; j4 < F4; j4++) acc[j4] = reinterpret_cast<float4*>(bl)[j4];

    // h[src] part (from registers)
    #pragma unroll
    for (int k4 = 0; k4 < H4; k4++) {
        float4 xv = hr[k4];
        #pragma unroll
        for (int c = 0; c < 4; c++) {
            float xc = (c == 0) ? xv.x : (c == 1) ? xv.y : (c == 2) ? xv.z : xv.w;
            const float4* wrow = &Wl[(k4 * 4 + c) * F4];
            #pragma unroll
            for (int j4 = 0; j4 < F4; j4++) fma4(acc[j4], wrow[j4], xc);
        }
    }
    // efeat part (from registers)
    #pragma unroll
    for (int k4 = 0; k4 < 16; k4++) {
        float4 xv = er[k4];
        #pragma unroll
        for (int c = 0; c < 4; c++) {
            float xc = (c == 0) ? xv.x : (c == 1) ? xv.y : (c == 2) ? xv.z : xv.w;
            const float4* wrow = &Wl[(FINP + k4 * 4 + c) * F4];
            #pragma unroll
            for (int j4 = 0; j4 < F4; j4++) fma4(acc[j4], wrow[j4], xc);
        }
    }

    __syncthreads();   // all W reads done; smem reused for messages

    const int lane = tid & 63;
    const int wv   = tid >> 6;

    #pragma unroll
    for (int half = 0; half < 2; ++half) {
        // owners of this half store relu(msg) + dst
        if ((tid >> 7) == half) {
            const int le = tid & 127;
            dhalf[le] = myD;
            #pragma unroll
            for (int j4 = 0; j4 < F4; j4++) {
                float4 a = acc[j4];
                if (4 * j4 + 0 < FOUT) msg[le * MS + 4 * j4 + 0] = fmaxf(a.x, 0.f);
                if (4 * j4 + 1 < FOUT) msg[le * MS + 4 * j4 + 1] = fmaxf(a.y, 0.f);
                if (4 * j4 + 2 < FOUT) msg[le * MS + 4 * j4 + 2] = fmaxf(a.z, 0.f);
                if (4 * j4 + 3 < FOUT) msg[le * MS + 4 * j4 + 3] = fmaxf(a.w, 0.f);
            }
        }
        __syncthreads();

        // segmented reduce: wave wv walks rows [wv*32, wv*32+32); lane=feature.
        for (int r = wv * 32; r < wv * 32 + 32; ++r) {
            int dr = dhalf[r];
            if (r > 0 && dhalf[r - 1] == dr) continue;   // not a segment start
            float s = 0.f;
            int rr = r;
            while (true) {
                s += msg[rr * MS + lane];
                ++rr;
                if (rr >= 128 || dhalf[rr] != dr) break;
            }
            if (lane < FOUT) atomicAdd(agg + (long long)dr * FOUT + lane, s);
        }
        __syncthreads();
    }
}

// ===========================================================================
// Node kernel: out = relu(cat(h, agg) @ W + b), one thread per node.
// ===========================================================================
template<int FH, int FHP, int FAGG, int FOUT, int FOUTP>
__global__ __launch_bounds__(256) void node_kernel(
    const float* __restrict__ h,
    const float* __restrict__ agg,
    const float* __restrict__ W,
    const float* __restrict__ b,
    float* __restrict__ out,
    int nNodes)
{
    constexpr int K  = FH + FAGG;
    constexpr int F4 = FOUTP / 4;

    __shared__ float4 Wl[K * F4];
    __shared__ float4 bl[F4];

    const int tid = threadIdx.x;
    for (int idx = tid; idx < K * FOUTP; idx += 256) {
        int k = idx / FOUTP;
        int j = idx - k * FOUTP;
        reinterpret_cast<float*>(Wl)[idx] = (j < FOUT) ? W[k * FOUT + j] : 0.f;
    }
    for (int idx = tid; idx < FOUTP; idx += 256)
        reinterpret_cast<float*>(bl)[idx] = (idx < FOUT) ? b[idx] : 0.f;
    __syncthreads();

    const int n = blockIdx.x * 256 + tid;
    if (n >= nNodes) return;

    float4 acc[F4];
    #pragma unroll
    for (int j4 = 0; j4 < F4; j4++) acc[j4] = bl[j4];

    const float* hrow = h + (long long)n * FHP;
    for (int k = 0; k < FH; k++) {
        float xk = hrow[k];
        const float4* wrow = &Wl[k * F4];
        #pragma unroll
        for (int j4 = 0; j4 < F4; j4++) fma4(acc[j4], wrow[j4], xk);
    }
    const float* arow = agg + (long long)n * FAGG;
    for (int k = 0; k < FAGG; k++) {
        float xk = arow[k];
        const float4* wrow = &Wl[(FH + k) * F4];
        #pragma unroll
        for (int j4 = 0; j4 < F4; j4++) fma4(acc[j4], wrow[j4], xk);
    }

    float4* orow = reinterpret_cast<float4*>(out + (long long)n * FOUTP);
    #pragma unroll
    for (int j4 = 0; j4 < F4; j4++) {
        float4 a = acc[j4];
        a.x = fmaxf(a.x, 0.f); a.y = fmaxf(a.y, 0.f);
        a.z = fmaxf(a.z, 0.f); a.w = fmaxf(a.w, 0.f);
        orow[j4] = a;
    }
}

extern "C" void kernel_launch(void* const* d_in, const int* in_sizes, int n_in,
                              void* d_out, int out_size, void* d_ws, size_t ws_size,
                              hipStream_t stream)
{
    const float* nfeats = (const float*)d_in[0];
    const float* efeats = (const float*)d_in[1];
    const int*   src    = (const int*)d_in[2];
    const int*   dst    = (const int*)d_in[3];
    const float* Wm1 = (const float*)d_in[4],  *bm1 = (const float*)d_in[5];
    const float* Wa1 = (const float*)d_in[6],  *ba1 = (const float*)d_in[7];
    const float* Wm2 = (const float*)d_in[8],  *bm2 = (const float*)d_in[9];
    const float* Wa2 = (const float*)d_in[10], *ba2 = (const float*)d_in[11];
    const float* Wm3 = (const float*)d_in[12], *bm3 = (const float*)d_in[13];
    const float* Wa3 = (const float*)d_in[14], *ba3 = (const float*)d_in[15];
    float* out = (float*)d_out;

    constexpr int N = 100000;
    constexpr int E = 3200000;               // divisible by 256
    constexpr int SCAN_BLOCKS = (N + 1023) / 1024;   // 98

    float* ws   = (float*)d_ws;
    float* h1   = ws;                         // N x 52
    float* h2   = h1 + (size_t)N * 52;        // N x 28
    float* agg  = h2 + (size_t)N * 28;        // N x 52
    int* counts = (int*)(agg + (size_t)N * 52);  // N
    int* cursor = counts + N;                    // N
    int* bsums  = cursor + N;                    // 128
    int* eidS   = bsums + 128;                   // E
    int* dS     = eidS + E;                      // E

    // ---- CSR build (counting sort by dst) ----
    hipMemsetAsync(counts, 0, (size_t)N * sizeof(int), stream);
    hist_kernel<<<2048, 256, 0, stream>>>(dst, counts, E);
    scan_block<<<SCAN_BLOCKS, 1024, 0, stream>>>(counts, cursor, bsums, N);
    scan_small<<<1, 64, 0, stream>>>(bsums, SCAN_BLOCKS);
    add_offsets<<<SCAN_BLOCKS, 1024, 0, stream>>>(cursor, bsums, N);
    scatter_kernel<<<2048, 256, 0, stream>>>(dst, cursor, eidS, dS, E);

    const int EB = E / 256;
    const int NB = (N + 255) / 256;

    // ---- layer 1 ----  edge: 64(+64) -> 50 (MS=51); node: 64+50 -> 50
    hipMemsetAsync(agg, 0, (size_t)N * 52 * sizeof(float), stream);
    edge_kernel<64, 64, 50, 52, 51><<<EB, 256, 0, stream>>>(nfeats, efeats, src, eidS, dS, Wm1, bm1, agg);
    node_kernel<64, 64, 50, 50, 52><<<NB, 256, 0, stream>>>(nfeats, agg, Wa1, ba1, h1, N);

    // ---- layer 2 ----  edge: 50(+64) -> 25 (MS=25); node: 50+25 -> 25
    hipMemsetAsync(agg, 0, (size_t)N * 52 * sizeof(float), stream);
    edge_kernel<50, 52, 25, 28, 25><<<EB, 256, 0, stream>>>(h1, efeats, src, eidS, dS, Wm2, bm2, agg);
    node_kernel<50, 52, 25, 25, 28><<<NB, 256, 0, stream>>>(h1, agg, Wa2, ba2, h2, N);

    // ---- layer 3 ----  edge: 25(+64) -> 32 (MS=33); node: 25+32 -> 32
    hipMemsetAsync(agg, 0, (size_t)N * 52 * sizeof(float), stream);
    edge_kernel<25, 28, 32, 32, 33><<<EB, 256, 0, stream>>>(h2, efeats, src, eidS, dS, Wm3, bm3, agg);
    node_kernel<25, 28, 32, 32, 32><<<NB, 256, 0, stream>>>(h2, agg, Wa3, ba3, out, N);
}